// Round 13
// baseline (185.644 us; speedup 1.0000x reference)
//
#include <hip/hip_runtime.h>

#define N_NODES 50000
#define N_EDGES 1600000
#define IN_CH 128
#define HEADS 4
#define HC 64                      // HEADS*OUT_CH
#define E_FULL (N_EDGES + N_NODES)
#define NEG_SLOPE 0.2f
#define HALF_COL 25000

#define BUCKET_NODES 98
#define NBUCK 512                  // 512*98 = 50176 >= 50000
#define BIN_TILE 2048              // edges per bin block (256 thr x 8)
#define NBLK_BIN ((N_EDGES + BIN_TILE - 1) / BIN_TILE)   // 782
#define T_FLAT (NBUCK * NBLK_BIN)                        // 400384
#define SCANA_BLOCKS (T_FLAT / 256)                      // 1564 (exact)

typedef __attribute__((ext_vector_type(8))) short short8v;
typedef __attribute__((ext_vector_type(4))) float float4v;

__device__ __forceinline__ float leaky(float s) { return s >= 0.f ? s : NEG_SLOPE * s; }

__device__ __forceinline__ unsigned f2bf(float f) {  // round-to-nearest-even
    unsigned u = __float_as_uint(f);
    return (u + 0x7fffu + ((u >> 16) & 1u)) >> 16;
}
__device__ __forceinline__ float bf2f(unsigned v) {
    return __uint_as_float(v << 16);
}

// ---------------- Kernel W: weight f32[128][64] -> bf16 wT[64][128] -------
__global__ __launch_bounds__(256) void wcvt_kernel(
    const float* __restrict__ w, unsigned short* __restrict__ wT)
{
    int i = blockIdx.x * 256 + threadIdx.x;
    if (i < IN_CH * HC) {
        int k = i >> 6, c = i & 63;
        wT[c * IN_CH + k] = (unsigned short)f2bf(w[i]);
    }
}

// ---------------- Kernel A: h = x @ W via MFMA, fused attention scalars ----
__global__ __launch_bounds__(256) void gemm_h_kernel(
    const float* __restrict__ x, const unsigned short* __restrict__ wT,
    const float* __restrict__ att, unsigned short* __restrict__ h16,
    float* __restrict__ s_src, float* __restrict__ s_dst)
{
    __shared__ unsigned short x_lds[64 * 128];   // 16 KB
    const int tid = threadIdx.x;
    const int nbase = blockIdx.x * 64;

    #pragma unroll
    for (int s = 0; s < 8; ++s) {
        int i = s * 256 + tid;            // float4 unit 0..2047
        int node = i >> 5;                // 0..63
        int q = i & 31;                   // float4 within row
        float4 v = make_float4(0.f, 0.f, 0.f, 0.f);
        int gn = nbase + node;
        if (gn < N_NODES) v = ((const float4*)x)[(size_t)gn * 32 + q];
        ushort4 b;
        b.x = (unsigned short)f2bf(v.x);
        b.y = (unsigned short)f2bf(v.y);
        b.z = (unsigned short)f2bf(v.z);
        b.w = (unsigned short)f2bf(v.w);
        int chunk = q >> 1, half = q & 1;
        int sw = chunk ^ (node & 7);
        *(ushort4*)&x_lds[node * 128 + sw * 8 + half * 4] = b;
    }
    __syncthreads();

    const int wid = tid >> 6, lane = tid & 63;
    const int g = lane >> 4, m = lane & 15;
    const int rt = wid;

    float4v acc[4] = {{0.f,0.f,0.f,0.f},{0.f,0.f,0.f,0.f},
                      {0.f,0.f,0.f,0.f},{0.f,0.f,0.f,0.f}};
    #pragma unroll
    for (int kk = 0; kk < 4; ++kk) {
        int chunk = (kk * 4 + g) ^ (m & 7);
        short8v a = *(const short8v*)&x_lds[(rt * 16 + m) * 128 + chunk * 8];
        #pragma unroll
        for (int ct = 0; ct < 4; ++ct) {
            short8v bfr = *(const short8v*)&wT[(ct * 16 + m) * IN_CH + kk * 32 + g * 8];
            acc[ct] = __builtin_amdgcn_mfma_f32_16x16x32_bf16(a, bfr, acc[ct], 0, 0, 0);
        }
    }

    #pragma unroll
    for (int ct = 0; ct < 4; ++ct) {
        float as = att[ct * 32 + m];
        float ad = att[ct * 32 + 16 + m];
        float ts[4], td[4];
        #pragma unroll
        for (int r = 0; r < 4; ++r) {
            int node = nbase + rt * 16 + g * 4 + r;
            float v = acc[ct][r];
            if (node < N_NODES)
                h16[(size_t)node * HC + ct * 16 + m] = (unsigned short)f2bf(v);
            ts[r] = v * as;
            td[r] = v * ad;
        }
        #pragma unroll
        for (int msk = 1; msk <= 8; msk <<= 1) {
            #pragma unroll
            for (int r = 0; r < 4; ++r) {
                ts[r] += __shfl_xor(ts[r], msk, 64);
                td[r] += __shfl_xor(td[r], msk, 64);
            }
        }
        if (m == 0) {
            #pragma unroll
            for (int r = 0; r < 4; ++r) {
                int node = nbase + rt * 16 + g * 4 + r;
                if (node < N_NODES) {
                    s_src[node * HEADS + ct] = ts[r];
                    s_dst[node * HEADS + ct] = td[r];
                }
            }
        }
    }
}

// ---------------- Kernel H: per-(block,bucket) histogram (ei row0 only) ---
__global__ __launch_bounds__(256) void histM_kernel(
    const int* __restrict__ ei, unsigned* __restrict__ M)
{
    __shared__ unsigned lh[NBUCK];
    const int tid = threadIdx.x;
    for (int j = tid; j < NBUCK; j += 256) lh[j] = 0;
    __syncthreads();
    const int base = blockIdx.x * BIN_TILE;
    #pragma unroll
    for (int k = 0; k < 8; ++k) {
        int e = base + k * 256 + tid;
        if (e < N_EDGES)
            atomicAdd(&lh[(unsigned)ei[e] / BUCKET_NODES], 1u);
    }
    __syncthreads();
    unsigned* Mb = M + (size_t)blockIdx.x * NBUCK;
    for (int j = tid; j < NBUCK; j += 256) Mb[j] = lh[j];
}

// ---------------- Scan over flattened [bucket][block] counts ---------------
__device__ __forceinline__ unsigned block_excl_scan(unsigned v, unsigned* total,
                                                    int tid) {
    const int lane = tid & 63, wid = tid >> 6;
    unsigned x = v;
    #pragma unroll
    for (int d = 1; d < 64; d <<= 1) {
        unsigned t = __shfl_up(x, d, 64);
        if (lane >= d) x += t;
    }
    __shared__ unsigned wsum[4];
    if (lane == 63) wsum[wid] = x;
    __syncthreads();
    unsigned woff = 0;
    for (int i = 0; i < wid; ++i) woff += wsum[i];
    unsigned incl = x + woff;
    if (tid == 255) *total = incl;
    return incl - v;
}

__global__ __launch_bounds__(256) void scanA_kernel(
    const unsigned* __restrict__ M, unsigned* __restrict__ localx,
    unsigned* __restrict__ partials)
{
    const int tid = threadIdx.x;
    const int f = blockIdx.x * 256 + tid;   // flat = bucket*NBLK_BIN + block
    unsigned v = 0;
    if (f < T_FLAT) {
        int bucket = f / NBLK_BIN;
        int blk = f - bucket * NBLK_BIN;
        v = M[(size_t)blk * NBUCK + bucket];
    }
    __shared__ unsigned tot;
    unsigned excl = block_excl_scan(v, &tot, tid);
    if (f < T_FLAT) localx[f] = excl;
    __syncthreads();
    if (tid == 0) partials[blockIdx.x] = tot;
}

__global__ __launch_bounds__(256) void scanB_kernel(
    const unsigned* __restrict__ partials, unsigned* __restrict__ pscan)
{
    __shared__ unsigned tot_sh;
    __shared__ unsigned carry_sh;
    const int tid = threadIdx.x;
    if (tid == 0) carry_sh = 0;
    __syncthreads();
    const int nchunk = (SCANA_BLOCKS + 255) / 256;
    for (int ch = 0; ch < nchunk; ++ch) {
        int i = ch * 256 + tid;
        unsigned v = (i < SCANA_BLOCKS) ? partials[i] : 0u;
        unsigned excl = block_excl_scan(v, &tot_sh, tid);
        unsigned carry = carry_sh;
        if (i < SCANA_BLOCKS) pscan[i] = excl + carry;
        __syncthreads();
        if (tid == 0) carry_sh += tot_sh;
        __syncthreads();
    }
}

__global__ __launch_bounds__(256) void scanC_kernel(
    const unsigned* __restrict__ localx, const unsigned* __restrict__ pscan,
    unsigned* __restrict__ S)
{
    const int f = blockIdx.x * 256 + threadIdx.x;
    if (f < T_FLAT) S[f] = localx[f] + pscan[blockIdx.x];
    if (f == 0) S[T_FLAT] = N_EDGES;
}

// ---------------- Kernel D: bin pass — alpha + eif + grouped slot writes --
__global__ __launch_bounds__(256) void bin_kernel(
    const int* __restrict__ ei, const float* __restrict__ ea,
    const float* __restrict__ s_src, const float* __restrict__ s_dst,
    const unsigned* __restrict__ S, uint4* __restrict__ slots,
    float* __restrict__ alpha, float* __restrict__ eif)
{
    __shared__ unsigned lh[NBUCK];
    __shared__ unsigned lbase[NBUCK];
    const int tid = threadIdx.x;
    for (int j = tid; j < NBUCK; j += 256) lh[j] = 0;
    __syncthreads();

    const int base = blockIdx.x * BIN_TILE;
    unsigned b8[8], idx8[8], p0[8], p1[8], p2[8];
    #pragma unroll
    for (int k = 0; k < 8; ++k) {
        int e = base + k * 256 + tid;
        b8[k] = 0xffffffffu;
        if (e < N_EDGES) {
            unsigned r = (unsigned)ei[e];
            unsigned c = (unsigned)ei[N_EDGES + e];
            float4 ss = ((const float4*)s_src)[r];
            float4 sd = ((const float4*)s_dst)[c];
            float4 eav = ((const float4*)ea)[e];
            float4 a;
            a.x = leaky(ss.x + sd.x) * eav.x;
            a.y = leaky(ss.y + sd.y) * eav.y;
            a.z = leaky(ss.z + sd.z) * eav.z;
            a.w = leaky(ss.w + sd.w) * eav.w;
            ((float4*)alpha)[e] = a;
            eif[e] = (float)r;
            eif[(size_t)E_FULL + e] = (float)c;

            unsigned bk = r / BUCKET_NODES;
            unsigned rl = r - bk * BUCKET_NODES;
            b8[k] = bk;
            p0[k] = c | (rl << 16);
            p1[k] = f2bf(a.x) | (f2bf(a.y) << 16);
            p2[k] = f2bf(a.z) | (f2bf(a.w) << 16);
            idx8[k] = atomicAdd(&lh[bk], 1u);
        }
    }
    __syncthreads();
    for (int j = tid; j < NBUCK; j += 256)
        lbase[j] = S[(size_t)j * NBLK_BIN + blockIdx.x];
    __syncthreads();
    #pragma unroll
    for (int k = 0; k < 8; ++k) {
        if (b8[k] != 0xffffffffu)
            slots[lbase[b8[k]] + idx8[k]] = make_uint4(p0[k], p1[k], p2[k], 0u);
    }
}

// ------- Kernel S: per-bucket counting sort by (node, col-half) key -------
__global__ __launch_bounds__(256) void sort_kernel(
    const unsigned* __restrict__ S, const uint4* __restrict__ slots,
    uint4* __restrict__ slots2, unsigned* __restrict__ offs,
    unsigned* __restrict__ mid)
{
    __shared__ unsigned cnt[BUCKET_NODES * 2];
    __shared__ unsigned cur[BUCKET_NODES * 2];
    const int b = blockIdx.x;
    const int tid = threadIdx.x;
    const unsigned start = S[(size_t)b * NBLK_BIN];
    const unsigned end   = S[(size_t)(b + 1) * NBLK_BIN];

    for (int j = tid; j < BUCKET_NODES * 2; j += 256) cnt[j] = 0;
    __syncthreads();
    for (unsigned i = start + tid; i < end; i += 256) {
        unsigned x0 = slots[i].x;
        unsigned key = ((x0 >> 16) << 1) | ((x0 & 0xffffu) >= HALF_COL ? 1u : 0u);
        atomicAdd(&cnt[key], 1u);
    }
    __syncthreads();
    if (tid == 0) {
        unsigned run = 0;
        for (int j = 0; j < BUCKET_NODES * 2; ++j) {
            unsigned c = cnt[j];
            cur[j] = run;
            run += c;
        }
    }
    __syncthreads();
    const int nstart = b * BUCKET_NODES;
    for (int j = tid; j < BUCKET_NODES; j += 256) {
        int n = nstart + j;
        if (n <= N_NODES) offs[n] = start + cur[2 * j];
        if (n < N_NODES)  mid[n]  = start + cur[2 * j + 1];
    }
    __syncthreads();
    for (unsigned i = start + tid; i < end; i += 256) {
        uint4 s = slots[i];
        unsigned key = ((s.x >> 16) << 1) | ((s.x & 0xffffu) >= HALF_COL ? 1u : 0u);
        unsigned pos = start + atomicAdd(&cur[key], 1u);
        slots2[pos] = s;
    }
}

// ---------------- Gather: two col-half passes, register accumulate -------
__device__ __forceinline__ float slot_alpha(uint4 s, int hd) {
    unsigned w = (hd & 2) ? s.z : s.y;
    return bf2f((hd & 1) ? (w >> 16) : (w & 0xffffu));
}

__device__ __forceinline__ float gather_range(
    const unsigned short* __restrict__ h16, const uint4* __restrict__ slots2,
    unsigned start, unsigned end, int lane, int hd, float acc)
{
    const int cnt = (int)(end - start);
    int i = 0;
    for (; i + 7 < cnt; i += 8) {
        uint4 sl[8];
        float hv[8];
        #pragma unroll
        for (int u = 0; u < 8; ++u) sl[u] = slots2[start + i + u];
        #pragma unroll
        for (int u = 0; u < 8; ++u)
            hv[u] = bf2f(h16[(size_t)(sl[u].x & 0xffffu) * HC + lane]);
        #pragma unroll
        for (int u = 0; u < 8; ++u)
            acc = fmaf(slot_alpha(sl[u], hd), hv[u], acc);
    }
    for (; i < cnt; ++i) {
        uint4 s0 = slots2[start + i];
        float h0 = bf2f(h16[(size_t)(s0.x & 0xffffu) * HC + lane]);
        acc = fmaf(slot_alpha(s0, hd), h0, acc);
    }
    return acc;
}

__global__ __launch_bounds__(256) void gatherA_kernel(
    const unsigned short* __restrict__ h16, const float* __restrict__ s_src,
    const float* __restrict__ s_dst, const float* __restrict__ bias,
    const unsigned* __restrict__ offs, const unsigned* __restrict__ mid,
    const uint4* __restrict__ slots2, float* __restrict__ out)
{
    const int tid = threadIdx.x;
    const int n = blockIdx.x * 4 + (tid >> 6);
    if (n >= N_NODES) return;
    const int lane = tid & 63, hd = lane >> 4;

    float s_self = s_src[n * HEADS + hd] + s_dst[n * HEADS + hd];
    float acc = bias[lane] + leaky(s_self) * bf2f(h16[(size_t)n * HC + lane]);
    acc = gather_range(h16, slots2, offs[n], mid[n], lane, hd, acc);
    out[(size_t)n * HC + lane] = acc;
}

__global__ __launch_bounds__(256) void gatherB_kernel(
    const unsigned short* __restrict__ h16, const float* __restrict__ s_src,
    const float* __restrict__ s_dst,
    const unsigned* __restrict__ offs, const unsigned* __restrict__ mid,
    const uint4* __restrict__ slots2, float* __restrict__ alpha,
    float* __restrict__ out, float* __restrict__ eif)
{
    const int tid = threadIdx.x;
    const int n = blockIdx.x * 4 + (tid >> 6);
    if (n >= N_NODES) return;
    const int lane = tid & 63, hd = lane >> 4;

    float acc = out[(size_t)n * HC + lane];
    acc = gather_range(h16, slots2, mid[n], offs[n + 1], lane, hd, acc);
    out[(size_t)n * HC + lane] = acc;

    if (lane < HEADS) {
        float s2 = s_src[n * HEADS + lane] + s_dst[n * HEADS + lane];
        alpha[(size_t)(N_EDGES + n) * HEADS + lane] = leaky(s2);
    }
    if (lane == 4) eif[N_EDGES + n] = (float)n;
    if (lane == 5) eif[(size_t)E_FULL + N_EDGES + n] = (float)n;
}

extern "C" void kernel_launch(void* const* d_in, const int* in_sizes, int n_in,
                              void* d_out, int out_size, void* d_ws, size_t ws_size,
                              hipStream_t stream) {
    const float* x      = (const float*)d_in[0];
    const int*   ei     = (const int*)  d_in[1];
    const float* ea     = (const float*)d_in[2];
    const float* weight = (const float*)d_in[3];
    const float* att    = (const float*)d_in[4];
    const float* bias   = (const float*)d_in[5];

    float* out   = (float*)d_out;                    // N_NODES*HC
    float* eif   = out + (size_t)N_NODES * HC;       // 2*E_FULL (as float)
    float* alpha = eif + (size_t)2 * E_FULL;         // E_FULL*HEADS

    // workspace layout (uint4 arrays first for 16B alignment); ~64.5 MB total
    uint4* slots  = (uint4*)d_ws;                                      // 25.6 MB
    uint4* slots2 = slots + (size_t)N_EDGES;                           // 25.6 MB
    unsigned short* wT = (unsigned short*)(slots2 + (size_t)N_EDGES);  // 16 KB
    unsigned short* h16 = wT + (size_t)IN_CH * HC;                     // 6.4 MB
    float* s_src = (float*)(h16 + (size_t)N_NODES * HC);               // 0.8 MB
    float* s_dst = s_src + (size_t)N_NODES * HEADS;                    // 0.8 MB
    unsigned* M        = (unsigned*)(s_dst + (size_t)N_NODES * HEADS); // 1.6 MB
    unsigned* localx   = M + (size_t)NBLK_BIN * NBUCK;                 // 1.6 MB
    unsigned* partials = localx + T_FLAT;                              // 6 KB
    unsigned* pscan    = partials + SCANA_BLOCKS;                      // 6 KB
    unsigned* S        = pscan + SCANA_BLOCKS;                         // 1.6 MB (T_FLAT+1)
    unsigned* offs     = S + (T_FLAT + 1);                             // N+1 u32
    unsigned* mid      = offs + (N_NODES + 1);                         // N u32

    wcvt_kernel<<<(IN_CH * HC + 255) / 256, 256, 0, stream>>>(weight, wT);
    gemm_h_kernel<<<(N_NODES + 63) / 64, 256, 0, stream>>>(x, wT, att, h16, s_src, s_dst);
    histM_kernel<<<NBLK_BIN, 256, 0, stream>>>(ei, M);
    scanA_kernel<<<SCANA_BLOCKS, 256, 0, stream>>>(M, localx, partials);
    scanB_kernel<<<1, 256, 0, stream>>>(partials, pscan);
    scanC_kernel<<<SCANA_BLOCKS, 256, 0, stream>>>(localx, pscan, S);
    bin_kernel<<<NBLK_BIN, 256, 0, stream>>>(ei, ea, s_src, s_dst, S, slots, alpha, eif);
    sort_kernel<<<NBUCK, 256, 0, stream>>>(S, slots, slots2, offs, mid);
    gatherA_kernel<<<(N_NODES + 3) / 4, 256, 0, stream>>>(
        h16, s_src, s_dst, bias, offs, mid, slots2, out);
    gatherB_kernel<<<(N_NODES + 3) / 4, 256, 0, stream>>>(
        h16, s_src, s_dst, offs, mid, slots2, alpha, out, eif);
}

// Round 14
// 176.969 us; speedup vs baseline: 1.0490x; 1.0490x over previous
//
#include <hip/hip_runtime.h>

#define N_NODES 50000
#define N_EDGES 1600000
#define IN_CH 128
#define HEADS 4
#define HC 64                      // HEADS*OUT_CH
#define E_FULL (N_EDGES + N_NODES)
#define NEG_SLOPE 0.2f

#define BUCKET_NODES 98
#define NBUCK 512                  // 512*98 = 50176 >= 50000
#define BIN_TILE 1024              // edges per bin block (256 thr x 4)
#define NBLK_BIN ((N_EDGES + BIN_TILE - 1) / BIN_TILE)   // 1563
#define T_FLAT (NBUCK * NBLK_BIN)                        // 800256
#define SCANA_BLOCKS (T_FLAT / 256)                      // 3126 (exact)

typedef __attribute__((ext_vector_type(8))) short short8v;
typedef __attribute__((ext_vector_type(4))) float float4v;

__device__ __forceinline__ float leaky(float s) { return s >= 0.f ? s : NEG_SLOPE * s; }

__device__ __forceinline__ unsigned f2bf(float f) {  // round-to-nearest-even
    unsigned u = __float_as_uint(f);
    return (u + 0x7fffu + ((u >> 16) & 1u)) >> 16;
}
__device__ __forceinline__ float bf2f(unsigned v) {
    return __uint_as_float(v << 16);
}

// ---------------- Kernel W: weight f32[128][64] -> bf16 wT[64][128] -------
__global__ __launch_bounds__(256) void wcvt_kernel(
    const float* __restrict__ w, unsigned short* __restrict__ wT)
{
    int i = blockIdx.x * 256 + threadIdx.x;
    if (i < IN_CH * HC) {
        int k = i >> 6, c = i & 63;
        wT[c * IN_CH + k] = (unsigned short)f2bf(w[i]);
    }
}

// ---------------- Kernel A: h = x @ W via MFMA, fused attention scalars ----
__global__ __launch_bounds__(256) void gemm_h_kernel(
    const float* __restrict__ x, const unsigned short* __restrict__ wT,
    const float* __restrict__ att, unsigned short* __restrict__ h16,
    float* __restrict__ s_src, float* __restrict__ s_dst)
{
    __shared__ unsigned short x_lds[64 * 128];   // 16 KB
    const int tid = threadIdx.x;
    const int nbase = blockIdx.x * 64;

    #pragma unroll
    for (int s = 0; s < 8; ++s) {
        int i = s * 256 + tid;            // float4 unit 0..2047
        int node = i >> 5;                // 0..63
        int q = i & 31;                   // float4 within row
        float4 v = make_float4(0.f, 0.f, 0.f, 0.f);
        int gn = nbase + node;
        if (gn < N_NODES) v = ((const float4*)x)[(size_t)gn * 32 + q];
        ushort4 b;
        b.x = (unsigned short)f2bf(v.x);
        b.y = (unsigned short)f2bf(v.y);
        b.z = (unsigned short)f2bf(v.z);
        b.w = (unsigned short)f2bf(v.w);
        int chunk = q >> 1, half = q & 1;
        int sw = chunk ^ (node & 7);
        *(ushort4*)&x_lds[node * 128 + sw * 8 + half * 4] = b;
    }
    __syncthreads();

    const int wid = tid >> 6, lane = tid & 63;
    const int g = lane >> 4, m = lane & 15;
    const int rt = wid;

    float4v acc[4] = {{0.f,0.f,0.f,0.f},{0.f,0.f,0.f,0.f},
                      {0.f,0.f,0.f,0.f},{0.f,0.f,0.f,0.f}};
    #pragma unroll
    for (int kk = 0; kk < 4; ++kk) {
        int chunk = (kk * 4 + g) ^ (m & 7);
        short8v a = *(const short8v*)&x_lds[(rt * 16 + m) * 128 + chunk * 8];
        #pragma unroll
        for (int ct = 0; ct < 4; ++ct) {
            short8v bfr = *(const short8v*)&wT[(ct * 16 + m) * IN_CH + kk * 32 + g * 8];
            acc[ct] = __builtin_amdgcn_mfma_f32_16x16x32_bf16(a, bfr, acc[ct], 0, 0, 0);
        }
    }

    #pragma unroll
    for (int ct = 0; ct < 4; ++ct) {
        float as = att[ct * 32 + m];
        float ad = att[ct * 32 + 16 + m];
        float ts[4], td[4];
        #pragma unroll
        for (int r = 0; r < 4; ++r) {
            int node = nbase + rt * 16 + g * 4 + r;
            float v = acc[ct][r];
            if (node < N_NODES)
                h16[(size_t)node * HC + ct * 16 + m] = (unsigned short)f2bf(v);
            ts[r] = v * as;
            td[r] = v * ad;
        }
        #pragma unroll
        for (int msk = 1; msk <= 8; msk <<= 1) {
            #pragma unroll
            for (int r = 0; r < 4; ++r) {
                ts[r] += __shfl_xor(ts[r], msk, 64);
                td[r] += __shfl_xor(td[r], msk, 64);
            }
        }
        if (m == 0) {
            #pragma unroll
            for (int r = 0; r < 4; ++r) {
                int node = nbase + rt * 16 + g * 4 + r;
                if (node < N_NODES) {
                    s_src[node * HEADS + ct] = ts[r];
                    s_dst[node * HEADS + ct] = td[r];
                }
            }
        }
    }
}

// ---------------- Kernel H: per-(block,bucket) histogram (ei row0 only) ---
__global__ __launch_bounds__(256) void histM_kernel(
    const int* __restrict__ ei, unsigned* __restrict__ M)
{
    __shared__ unsigned lh[NBUCK];
    const int tid = threadIdx.x;
    for (int j = tid; j < NBUCK; j += 256) lh[j] = 0;
    __syncthreads();
    const int base = blockIdx.x * BIN_TILE;
    #pragma unroll
    for (int k = 0; k < 4; ++k) {
        int e = base + k * 256 + tid;
        if (e < N_EDGES)
            atomicAdd(&lh[(unsigned)ei[e] / BUCKET_NODES], 1u);
    }
    __syncthreads();
    unsigned* Mb = M + (size_t)blockIdx.x * NBUCK;
    for (int j = tid; j < NBUCK; j += 256) Mb[j] = lh[j];
}

// ---------------- Scan over flattened [bucket][block] counts ---------------
__device__ __forceinline__ unsigned block_excl_scan(unsigned v, unsigned* total,
                                                    int tid) {
    const int lane = tid & 63, wid = tid >> 6;
    unsigned x = v;
    #pragma unroll
    for (int d = 1; d < 64; d <<= 1) {
        unsigned t = __shfl_up(x, d, 64);
        if (lane >= d) x += t;
    }
    __shared__ unsigned wsum[4];
    if (lane == 63) wsum[wid] = x;
    __syncthreads();
    unsigned woff = 0;
    for (int i = 0; i < wid; ++i) woff += wsum[i];
    unsigned incl = x + woff;
    if (tid == 255) *total = incl;
    return incl - v;
}

__global__ __launch_bounds__(256) void scanA_kernel(
    const unsigned* __restrict__ M, unsigned* __restrict__ S,
    unsigned* __restrict__ partials)
{
    const int tid = threadIdx.x;
    const int f = blockIdx.x * 256 + tid;   // flat = bucket*NBLK_BIN + block
    unsigned v = 0;
    if (f < T_FLAT) {
        int bucket = f / NBLK_BIN;
        int blk = f - bucket * NBLK_BIN;
        v = M[(size_t)blk * NBUCK + bucket];
    }
    __shared__ unsigned tot;
    unsigned excl = block_excl_scan(v, &tot, tid);
    if (f < T_FLAT) S[f] = excl;
    __syncthreads();
    if (tid == 0) partials[blockIdx.x] = tot;
}

__global__ __launch_bounds__(256) void scanB_kernel(
    const unsigned* __restrict__ partials, unsigned* __restrict__ pscan)
{
    __shared__ unsigned tot_sh;
    __shared__ unsigned carry_sh;
    const int tid = threadIdx.x;
    if (tid == 0) carry_sh = 0;
    __syncthreads();
    const int nchunk = (SCANA_BLOCKS + 255) / 256;
    for (int ch = 0; ch < nchunk; ++ch) {
        int i = ch * 256 + tid;
        unsigned v = (i < SCANA_BLOCKS) ? partials[i] : 0u;
        unsigned excl = block_excl_scan(v, &tot_sh, tid);
        unsigned carry = carry_sh;
        if (i < SCANA_BLOCKS) pscan[i] = excl + carry;
        __syncthreads();
        if (tid == 0) carry_sh += tot_sh;
        __syncthreads();
    }
}

__global__ __launch_bounds__(256) void scanC_kernel(
    const unsigned* __restrict__ pscan, unsigned* __restrict__ S)
{
    const int f = blockIdx.x * 256 + threadIdx.x;
    if (f < T_FLAT) S[f] += pscan[blockIdx.x];
    if (f == 0) S[T_FLAT] = N_EDGES;
}

// ---------------- Kernel D: bin pass — phased loads for MLP ---------------
__global__ __launch_bounds__(256) void bin_kernel(
    const int* __restrict__ ei, const float* __restrict__ ea,
    const float* __restrict__ s_src, const float* __restrict__ s_dst,
    const unsigned* __restrict__ S, uint4* __restrict__ slots,
    float* __restrict__ alpha, float* __restrict__ eif)
{
    __shared__ unsigned lh[NBUCK];
    __shared__ unsigned lbase[NBUCK];
    const int tid = threadIdx.x;
    for (int j = tid; j < NBUCK; j += 256) lh[j] = 0;
    __syncthreads();

    const int base = blockIdx.x * BIN_TILE;

    // phase 1: issue all ei loads
    int r4[4], c4[4];
    #pragma unroll
    for (int k = 0; k < 4; ++k) {
        int e = base + k * 256 + tid;
        r4[k] = (e < N_EDGES) ? ei[e] : -1;
        c4[k] = (e < N_EDGES) ? ei[N_EDGES + e] : 0;
    }
    // phase 2: issue all table loads (12 independent float4 loads)
    float4 ss[4], sd[4], eav[4];
    #pragma unroll
    for (int k = 0; k < 4; ++k) {
        if (r4[k] >= 0) {
            ss[k]  = ((const float4*)s_src)[r4[k]];
            sd[k]  = ((const float4*)s_dst)[c4[k]];
            eav[k] = ((const float4*)ea)[base + k * 256 + tid];
        }
    }
    // phase 3: compute, sequential writes, LDS hist
    unsigned b4[4], idx4[4], p0[4], p1[4], p2[4];
    #pragma unroll
    for (int k = 0; k < 4; ++k) {
        b4[k] = 0xffffffffu;
        if (r4[k] >= 0) {
            int e = base + k * 256 + tid;
            unsigned r = (unsigned)r4[k], c = (unsigned)c4[k];
            float4 a;
            a.x = leaky(ss[k].x + sd[k].x) * eav[k].x;
            a.y = leaky(ss[k].y + sd[k].y) * eav[k].y;
            a.z = leaky(ss[k].z + sd[k].z) * eav[k].z;
            a.w = leaky(ss[k].w + sd[k].w) * eav[k].w;
            ((float4*)alpha)[e] = a;
            eif[e] = (float)r;
            eif[(size_t)E_FULL + e] = (float)c;

            unsigned bk = r / BUCKET_NODES;
            unsigned rl = r - bk * BUCKET_NODES;
            b4[k] = bk;
            p0[k] = c | (rl << 16);
            p1[k] = f2bf(a.x) | (f2bf(a.y) << 16);
            p2[k] = f2bf(a.z) | (f2bf(a.w) << 16);
            idx4[k] = atomicAdd(&lh[bk], 1u);
        }
    }
    __syncthreads();
    for (int j = tid; j < NBUCK; j += 256)
        lbase[j] = S[(size_t)j * NBLK_BIN + blockIdx.x];
    __syncthreads();
    #pragma unroll
    for (int k = 0; k < 4; ++k) {
        if (b4[k] != 0xffffffffu)
            slots[lbase[b4[k]] + idx4[k]] = make_uint4(p0[k], p1[k], p2[k], 0u);
    }
}

// ---------------- Kernel S: per-bucket counting sort -> node-sorted slots --
__global__ __launch_bounds__(256) void sort_kernel(
    const unsigned* __restrict__ S, const uint4* __restrict__ slots,
    uint4* __restrict__ slots2, unsigned* __restrict__ offs)
{
    __shared__ unsigned cnt[BUCKET_NODES];
    __shared__ unsigned cur[BUCKET_NODES];
    const int b = blockIdx.x;
    const int tid = threadIdx.x;
    const unsigned start = S[(size_t)b * NBLK_BIN];
    const unsigned end   = S[(size_t)(b + 1) * NBLK_BIN];

    for (int j = tid; j < BUCKET_NODES; j += 256) cnt[j] = 0;
    __syncthreads();
    for (unsigned i = start + tid; i < end; i += 256)
        atomicAdd(&cnt[slots[i].x >> 16], 1u);
    __syncthreads();
    if (tid == 0) {
        unsigned run = 0;
        for (int j = 0; j < BUCKET_NODES; ++j) {
            unsigned c = cnt[j];
            cur[j] = run;
            run += c;
        }
    }
    __syncthreads();
    const int nstart = b * BUCKET_NODES;
    for (int j = tid; j < BUCKET_NODES; j += 256) {
        int n = nstart + j;
        if (n <= N_NODES) offs[n] = start + cur[j];
    }
    __syncthreads();
    for (unsigned i = start + tid; i < end; i += 256) {
        uint4 s = slots[i];
        unsigned rl = s.x >> 16;
        unsigned pos = start + atomicAdd(&cur[rl], 1u);
        slots2[pos] = s;
    }
}

// ---------------- Kernel E: per-node register gather (8-deep MLP) ---------
__device__ __forceinline__ float slot_alpha(uint4 s, int hd) {
    unsigned w = (hd & 2) ? s.z : s.y;
    return bf2f((hd & 1) ? (w >> 16) : (w & 0xffffu));
}

__global__ __launch_bounds__(256) void gather_kernel(
    const unsigned short* __restrict__ h16, const float* __restrict__ s_src,
    const float* __restrict__ s_dst, const float* __restrict__ bias,
    const unsigned* __restrict__ offs, const uint4* __restrict__ slots2,
    float* __restrict__ alpha, float* __restrict__ out, float* __restrict__ eif)
{
    const int tid = threadIdx.x;
    const int n = blockIdx.x * 4 + (tid >> 6);
    if (n >= N_NODES) return;
    const int lane = tid & 63, hd = lane >> 4;

    float s_self = s_src[n * HEADS + hd] + s_dst[n * HEADS + hd];
    float acc = bias[lane] + leaky(s_self) * bf2f(h16[(size_t)n * HC + lane]);

    const unsigned start = offs[n];
    const int cnt = (int)(offs[n + 1] - start);

    int i = 0;
    for (; i + 7 < cnt; i += 8) {
        uint4 sl[8];
        float hv[8];
        #pragma unroll
        for (int u = 0; u < 8; ++u) sl[u] = slots2[start + i + u];
        #pragma unroll
        for (int u = 0; u < 8; ++u)
            hv[u] = bf2f(h16[(size_t)(sl[u].x & 0xffffu) * HC + lane]);
        #pragma unroll
        for (int u = 0; u < 8; ++u)
            acc = fmaf(slot_alpha(sl[u], hd), hv[u], acc);
    }
    for (; i < cnt; ++i) {
        uint4 s0 = slots2[start + i];
        float h0 = bf2f(h16[(size_t)(s0.x & 0xffffu) * HC + lane]);
        acc = fmaf(slot_alpha(s0, hd), h0, acc);
    }
    out[(size_t)n * HC + lane] = acc;

    if (lane < HEADS) {
        float s2 = s_src[n * HEADS + lane] + s_dst[n * HEADS + lane];
        alpha[(size_t)(N_EDGES + n) * HEADS + lane] = leaky(s2);
    }
    if (lane == 4) eif[N_EDGES + n] = (float)n;
    if (lane == 5) eif[(size_t)E_FULL + N_EDGES + n] = (float)n;
}

extern "C" void kernel_launch(void* const* d_in, const int* in_sizes, int n_in,
                              void* d_out, int out_size, void* d_ws, size_t ws_size,
                              hipStream_t stream) {
    const float* x      = (const float*)d_in[0];
    const int*   ei     = (const int*)  d_in[1];
    const float* ea     = (const float*)d_in[2];
    const float* weight = (const float*)d_in[3];
    const float* att    = (const float*)d_in[4];
    const float* bias   = (const float*)d_in[5];

    float* out   = (float*)d_out;                    // N_NODES*HC
    float* eif   = out + (size_t)N_NODES * HC;       // 2*E_FULL (as float)
    float* alpha = eif + (size_t)2 * E_FULL;         // E_FULL*HEADS

    // workspace layout (uint4 arrays first for 16B alignment); ~66 MB total
    uint4* slots  = (uint4*)d_ws;                                      // 25.6 MB
    uint4* slots2 = slots + (size_t)N_EDGES;                           // 25.6 MB
    unsigned short* wT = (unsigned short*)(slots2 + (size_t)N_EDGES);  // 16 KB
    unsigned short* h16 = wT + (size_t)IN_CH * HC;                     // 6.4 MB
    float* s_src = (float*)(h16 + (size_t)N_NODES * HC);               // 0.8 MB
    float* s_dst = s_src + (size_t)N_NODES * HEADS;                    // 0.8 MB
    unsigned* M        = (unsigned*)(s_dst + (size_t)N_NODES * HEADS); // 3.2 MB
    unsigned* partials = M + (size_t)NBLK_BIN * NBUCK;                 // 12.5 KB
    unsigned* pscan    = partials + SCANA_BLOCKS;                      // 12.5 KB
    unsigned* S        = pscan + SCANA_BLOCKS;                         // 3.2 MB (T_FLAT+1)
    unsigned* offs     = S + (T_FLAT + 1);                             // N+1 u32

    wcvt_kernel<<<(IN_CH * HC + 255) / 256, 256, 0, stream>>>(weight, wT);
    gemm_h_kernel<<<(N_NODES + 63) / 64, 256, 0, stream>>>(x, wT, att, h16, s_src, s_dst);
    histM_kernel<<<NBLK_BIN, 256, 0, stream>>>(ei, M);
    scanA_kernel<<<SCANA_BLOCKS, 256, 0, stream>>>(M, S, partials);
    scanB_kernel<<<1, 256, 0, stream>>>(partials, pscan);
    scanC_kernel<<<SCANA_BLOCKS, 256, 0, stream>>>(pscan, S);
    bin_kernel<<<NBLK_BIN, 256, 0, stream>>>(ei, ea, s_src, s_dst, S, slots, alpha, eif);
    sort_kernel<<<NBUCK, 256, 0, stream>>>(S, slots, slots2, offs);
    gather_kernel<<<(N_NODES + 3) / 4, 256, 0, stream>>>(
        h16, s_src, s_dst, bias, offs, slots2, alpha, out, eif);
}

// Round 15
// 170.592 us; speedup vs baseline: 1.0882x; 1.0374x over previous
//
#include <hip/hip_runtime.h>

#define N_NODES 50000
#define N_EDGES 1600000
#define IN_CH 128
#define HEADS 4
#define HC 64                      // HEADS*OUT_CH
#define E_FULL (N_EDGES + N_NODES)
#define NEG_SLOPE 0.2f

#define BUCKET_NODES 98
#define NBUCK 512                  // 512*98 = 50176 >= 50000
#define BIN_TILE 2048              // edges per bin block (256 thr x 8)
#define NBLK_BIN ((N_EDGES + BIN_TILE - 1) / BIN_TILE)   // 782
#define T_FLAT (NBUCK * NBLK_BIN)                        // 400384
#define SCANA_BLOCKS (T_FLAT / 256)                      // 1564 (exact)

typedef __attribute__((ext_vector_type(8))) short short8v;
typedef __attribute__((ext_vector_type(4))) float float4v;

__device__ __forceinline__ float leaky(float s) { return s >= 0.f ? s : NEG_SLOPE * s; }

__device__ __forceinline__ unsigned f2bf(float f) {  // round-to-nearest-even
    unsigned u = __float_as_uint(f);
    return (u + 0x7fffu + ((u >> 16) & 1u)) >> 16;
}
__device__ __forceinline__ float bf2f(unsigned v) {
    return __uint_as_float(v << 16);
}

// ---------------- Kernel W: weight f32[128][64] -> bf16 wT[64][128] -------
__global__ __launch_bounds__(256) void wcvt_kernel(
    const float* __restrict__ w, unsigned short* __restrict__ wT)
{
    int i = blockIdx.x * 256 + threadIdx.x;
    if (i < IN_CH * HC) {
        int k = i >> 6, c = i & 63;
        wT[c * IN_CH + k] = (unsigned short)f2bf(w[i]);
    }
}

// ---------------- Kernel A: h = x @ W via MFMA, fused attention scalars ----
__global__ __launch_bounds__(256) void gemm_h_kernel(
    const float* __restrict__ x, const unsigned short* __restrict__ wT,
    const float* __restrict__ att, unsigned short* __restrict__ h16,
    float* __restrict__ s_src, float* __restrict__ s_dst)
{
    __shared__ unsigned short x_lds[64 * 128];   // 16 KB
    const int tid = threadIdx.x;
    const int nbase = blockIdx.x * 64;

    #pragma unroll
    for (int s = 0; s < 8; ++s) {
        int i = s * 256 + tid;            // float4 unit 0..2047
        int node = i >> 5;                // 0..63
        int q = i & 31;                   // float4 within row
        float4 v = make_float4(0.f, 0.f, 0.f, 0.f);
        int gn = nbase + node;
        if (gn < N_NODES) v = ((const float4*)x)[(size_t)gn * 32 + q];
        ushort4 b;
        b.x = (unsigned short)f2bf(v.x);
        b.y = (unsigned short)f2bf(v.y);
        b.z = (unsigned short)f2bf(v.z);
        b.w = (unsigned short)f2bf(v.w);
        int chunk = q >> 1, half = q & 1;
        int sw = chunk ^ (node & 7);
        *(ushort4*)&x_lds[node * 128 + sw * 8 + half * 4] = b;
    }
    __syncthreads();

    const int wid = tid >> 6, lane = tid & 63;
    const int g = lane >> 4, m = lane & 15;
    const int rt = wid;

    float4v acc[4] = {{0.f,0.f,0.f,0.f},{0.f,0.f,0.f,0.f},
                      {0.f,0.f,0.f,0.f},{0.f,0.f,0.f,0.f}};
    #pragma unroll
    for (int kk = 0; kk < 4; ++kk) {
        int chunk = (kk * 4 + g) ^ (m & 7);
        short8v a = *(const short8v*)&x_lds[(rt * 16 + m) * 128 + chunk * 8];
        #pragma unroll
        for (int ct = 0; ct < 4; ++ct) {
            short8v bfr = *(const short8v*)&wT[(ct * 16 + m) * IN_CH + kk * 32 + g * 8];
            acc[ct] = __builtin_amdgcn_mfma_f32_16x16x32_bf16(a, bfr, acc[ct], 0, 0, 0);
        }
    }

    #pragma unroll
    for (int ct = 0; ct < 4; ++ct) {
        float as = att[ct * 32 + m];
        float ad = att[ct * 32 + 16 + m];
        float ts[4], td[4];
        #pragma unroll
        for (int r = 0; r < 4; ++r) {
            int node = nbase + rt * 16 + g * 4 + r;
            float v = acc[ct][r];
            if (node < N_NODES)
                h16[(size_t)node * HC + ct * 16 + m] = (unsigned short)f2bf(v);
            ts[r] = v * as;
            td[r] = v * ad;
        }
        #pragma unroll
        for (int msk = 1; msk <= 8; msk <<= 1) {
            #pragma unroll
            for (int r = 0; r < 4; ++r) {
                ts[r] += __shfl_xor(ts[r], msk, 64);
                td[r] += __shfl_xor(td[r], msk, 64);
            }
        }
        if (m == 0) {
            #pragma unroll
            for (int r = 0; r < 4; ++r) {
                int node = nbase + rt * 16 + g * 4 + r;
                if (node < N_NODES) {
                    s_src[node * HEADS + ct] = ts[r];
                    s_dst[node * HEADS + ct] = td[r];
                }
            }
        }
    }
}

// ---------------- Kernel H: per-(block,bucket) histogram (ei row0 only) ---
__global__ __launch_bounds__(256) void histM_kernel(
    const int* __restrict__ ei, unsigned* __restrict__ M)
{
    __shared__ unsigned lh[NBUCK];
    const int tid = threadIdx.x;
    for (int j = tid; j < NBUCK; j += 256) lh[j] = 0;
    __syncthreads();
    const int base = blockIdx.x * BIN_TILE;
    #pragma unroll
    for (int k = 0; k < 8; ++k) {
        int e = base + k * 256 + tid;
        if (e < N_EDGES)
            atomicAdd(&lh[(unsigned)ei[e] / BUCKET_NODES], 1u);
    }
    __syncthreads();
    unsigned* Mb = M + (size_t)blockIdx.x * NBUCK;
    for (int j = tid; j < NBUCK; j += 256) Mb[j] = lh[j];
}

// ---------------- Scan over flattened [bucket][block] counts ---------------
__device__ __forceinline__ unsigned block_excl_scan(unsigned v, unsigned* total,
                                                    int tid) {
    const int lane = tid & 63, wid = tid >> 6;
    unsigned x = v;
    #pragma unroll
    for (int d = 1; d < 64; d <<= 1) {
        unsigned t = __shfl_up(x, d, 64);
        if (lane >= d) x += t;
    }
    __shared__ unsigned wsum[4];
    if (lane == 63) wsum[wid] = x;
    __syncthreads();
    unsigned woff = 0;
    for (int i = 0; i < wid; ++i) woff += wsum[i];
    unsigned incl = x + woff;
    if (tid == 255) *total = incl;
    return incl - v;
}

__global__ __launch_bounds__(256) void scanA_kernel(
    const unsigned* __restrict__ M, unsigned* __restrict__ localx,
    unsigned* __restrict__ partials)
{
    const int tid = threadIdx.x;
    const int f = blockIdx.x * 256 + tid;   // flat = bucket*NBLK_BIN + block
    unsigned v = 0;
    if (f < T_FLAT) {
        int bucket = f / NBLK_BIN;
        int blk = f - bucket * NBLK_BIN;
        v = M[(size_t)blk * NBUCK + bucket];
    }
    __shared__ unsigned tot;
    unsigned excl = block_excl_scan(v, &tot, tid);
    if (f < T_FLAT) localx[f] = excl;
    __syncthreads();
    if (tid == 0) partials[blockIdx.x] = tot;
}

__global__ __launch_bounds__(256) void scanB_kernel(
    const unsigned* __restrict__ partials, unsigned* __restrict__ pscan)
{
    __shared__ unsigned tot_sh;
    __shared__ unsigned carry_sh;
    const int tid = threadIdx.x;
    if (tid == 0) carry_sh = 0;
    __syncthreads();
    const int nchunk = (SCANA_BLOCKS + 255) / 256;
    for (int ch = 0; ch < nchunk; ++ch) {
        int i = ch * 256 + tid;
        unsigned v = (i < SCANA_BLOCKS) ? partials[i] : 0u;
        unsigned excl = block_excl_scan(v, &tot_sh, tid);
        unsigned carry = carry_sh;
        if (i < SCANA_BLOCKS) pscan[i] = excl + carry;
        __syncthreads();
        if (tid == 0) carry_sh += tot_sh;
        __syncthreads();
    }
}

__global__ __launch_bounds__(256) void scanC_kernel(
    const unsigned* __restrict__ localx, const unsigned* __restrict__ pscan,
    unsigned* __restrict__ S)
{
    const int f = blockIdx.x * 256 + threadIdx.x;
    if (f < T_FLAT) S[f] = localx[f] + pscan[blockIdx.x];
    if (f == 0) S[T_FLAT] = N_EDGES;
}

// ------- Kernel D: bin pass — phased loads (MLP), grouped slot writes -----
__global__ __launch_bounds__(256) void bin_kernel(
    const int* __restrict__ ei, const float* __restrict__ ea,
    const float* __restrict__ s_src, const float* __restrict__ s_dst,
    const unsigned* __restrict__ S, uint4* __restrict__ slots,
    float* __restrict__ alpha, float* __restrict__ eif)
{
    __shared__ unsigned lh[NBUCK];
    __shared__ unsigned lbase[NBUCK];
    const int tid = threadIdx.x;
    for (int j = tid; j < NBUCK; j += 256) lh[j] = 0;
    __syncthreads();

    const int base = blockIdx.x * BIN_TILE;

    // phase 1: issue all 16 ei loads
    int r8[8], c8[8];
    #pragma unroll
    for (int k = 0; k < 8; ++k) {
        int e = base + k * 256 + tid;
        r8[k] = (e < N_EDGES) ? ei[e] : -1;
        c8[k] = (e < N_EDGES) ? ei[N_EDGES + e] : 0;
    }
    // phase 2: issue all 24 independent table loads
    float4 ss[8], sd[8], eav[8];
    #pragma unroll
    for (int k = 0; k < 8; ++k) {
        if (r8[k] >= 0) {
            ss[k]  = ((const float4*)s_src)[r8[k]];
            sd[k]  = ((const float4*)s_dst)[c8[k]];
            eav[k] = ((const float4*)ea)[base + k * 256 + tid];
        }
    }
    // phase 3: compute, sequential alpha/eif writes, LDS hist
    unsigned b8[8], idx8[8], p0[8], p1[8], p2[8];
    #pragma unroll
    for (int k = 0; k < 8; ++k) {
        b8[k] = 0xffffffffu;
        if (r8[k] >= 0) {
            int e = base + k * 256 + tid;
            unsigned r = (unsigned)r8[k], c = (unsigned)c8[k];
            float4 a;
            a.x = leaky(ss[k].x + sd[k].x) * eav[k].x;
            a.y = leaky(ss[k].y + sd[k].y) * eav[k].y;
            a.z = leaky(ss[k].z + sd[k].z) * eav[k].z;
            a.w = leaky(ss[k].w + sd[k].w) * eav[k].w;
            ((float4*)alpha)[e] = a;
            eif[e] = (float)r;
            eif[(size_t)E_FULL + e] = (float)c;

            unsigned bk = r / BUCKET_NODES;
            unsigned rl = r - bk * BUCKET_NODES;
            b8[k] = bk;
            p0[k] = c | (rl << 16);
            p1[k] = f2bf(a.x) | (f2bf(a.y) << 16);
            p2[k] = f2bf(a.z) | (f2bf(a.w) << 16);
            idx8[k] = atomicAdd(&lh[bk], 1u);
        }
    }
    __syncthreads();
    for (int j = tid; j < NBUCK; j += 256)
        lbase[j] = S[(size_t)j * NBLK_BIN + blockIdx.x];
    __syncthreads();
    #pragma unroll
    for (int k = 0; k < 8; ++k) {
        if (b8[k] != 0xffffffffu)
            slots[lbase[b8[k]] + idx8[k]] = make_uint4(p0[k], p1[k], p2[k], 0u);
    }
}

// ---------------- Kernel S: per-bucket counting sort -> node-sorted slots --
__global__ __launch_bounds__(256) void sort_kernel(
    const unsigned* __restrict__ S, const uint4* __restrict__ slots,
    uint4* __restrict__ slots2, unsigned* __restrict__ offs)
{
    __shared__ unsigned cnt[BUCKET_NODES];
    __shared__ unsigned cur[BUCKET_NODES];
    const int b = blockIdx.x;
    const int tid = threadIdx.x;
    const unsigned start = S[(size_t)b * NBLK_BIN];
    const unsigned end   = S[(size_t)(b + 1) * NBLK_BIN];

    for (int j = tid; j < BUCKET_NODES; j += 256) cnt[j] = 0;
    __syncthreads();
    for (unsigned i = start + tid; i < end; i += 256)
        atomicAdd(&cnt[slots[i].x >> 16], 1u);
    __syncthreads();
    if (tid == 0) {
        unsigned run = 0;
        for (int j = 0; j < BUCKET_NODES; ++j) {
            unsigned c = cnt[j];
            cur[j] = run;
            run += c;
        }
    }
    __syncthreads();
    const int nstart = b * BUCKET_NODES;
    for (int j = tid; j < BUCKET_NODES; j += 256) {
        int n = nstart + j;
        if (n <= N_NODES) offs[n] = start + cur[j];
    }
    __syncthreads();
    for (unsigned i = start + tid; i < end; i += 256) {
        uint4 s = slots[i];
        unsigned rl = s.x >> 16;
        unsigned pos = start + atomicAdd(&cur[rl], 1u);
        slots2[pos] = s;
    }
}

// ---------------- Kernel E: per-node register gather (8-deep MLP) ---------
__device__ __forceinline__ float slot_alpha(uint4 s, int hd) {
    unsigned w = (hd & 2) ? s.z : s.y;
    return bf2f((hd & 1) ? (w >> 16) : (w & 0xffffu));
}

__global__ __launch_bounds__(256) void gather_kernel(
    const unsigned short* __restrict__ h16, const float* __restrict__ s_src,
    const float* __restrict__ s_dst, const float* __restrict__ bias,
    const unsigned* __restrict__ offs, const uint4* __restrict__ slots2,
    float* __restrict__ alpha, float* __restrict__ out, float* __restrict__ eif)
{
    const int tid = threadIdx.x;
    const int n = blockIdx.x * 4 + (tid >> 6);
    if (n >= N_NODES) return;
    const int lane = tid & 63, hd = lane >> 4;

    float s_self = s_src[n * HEADS + hd] + s_dst[n * HEADS + hd];
    float acc = bias[lane] + leaky(s_self) * bf2f(h16[(size_t)n * HC + lane]);

    const unsigned start = offs[n];
    const int cnt = (int)(offs[n + 1] - start);

    int i = 0;
    for (; i + 7 < cnt; i += 8) {
        uint4 sl[8];
        float hv[8];
        #pragma unroll
        for (int u = 0; u < 8; ++u) sl[u] = slots2[start + i + u];
        #pragma unroll
        for (int u = 0; u < 8; ++u)
            hv[u] = bf2f(h16[(size_t)(sl[u].x & 0xffffu) * HC + lane]);
        #pragma unroll
        for (int u = 0; u < 8; ++u)
            acc = fmaf(slot_alpha(sl[u], hd), hv[u], acc);
    }
    for (; i < cnt; ++i) {
        uint4 s0 = slots2[start + i];
        float h0 = bf2f(h16[(size_t)(s0.x & 0xffffu) * HC + lane]);
        acc = fmaf(slot_alpha(s0, hd), h0, acc);
    }
    out[(size_t)n * HC + lane] = acc;

    if (lane < HEADS) {
        float s2 = s_src[n * HEADS + lane] + s_dst[n * HEADS + lane];
        alpha[(size_t)(N_EDGES + n) * HEADS + lane] = leaky(s2);
    }
    if (lane == 4) eif[N_EDGES + n] = (float)n;
    if (lane == 5) eif[(size_t)E_FULL + N_EDGES + n] = (float)n;
}

extern "C" void kernel_launch(void* const* d_in, const int* in_sizes, int n_in,
                              void* d_out, int out_size, void* d_ws, size_t ws_size,
                              hipStream_t stream) {
    const float* x      = (const float*)d_in[0];
    const int*   ei     = (const int*)  d_in[1];
    const float* ea     = (const float*)d_in[2];
    const float* weight = (const float*)d_in[3];
    const float* att    = (const float*)d_in[4];
    const float* bias   = (const float*)d_in[5];

    float* out   = (float*)d_out;                    // N_NODES*HC
    float* eif   = out + (size_t)N_NODES * HC;       // 2*E_FULL (as float)
    float* alpha = eif + (size_t)2 * E_FULL;         // E_FULL*HEADS

    // workspace layout (uint4 arrays first for 16B alignment); ~64.3 MB total
    uint4* slots  = (uint4*)d_ws;                                      // 25.6 MB
    uint4* slots2 = slots + (size_t)N_EDGES;                           // 25.6 MB
    unsigned short* wT = (unsigned short*)(slots2 + (size_t)N_EDGES);  // 16 KB
    unsigned short* h16 = wT + (size_t)IN_CH * HC;                     // 6.4 MB
    float* s_src = (float*)(h16 + (size_t)N_NODES * HC);               // 0.8 MB
    float* s_dst = s_src + (size_t)N_NODES * HEADS;                    // 0.8 MB
    unsigned* M        = (unsigned*)(s_dst + (size_t)N_NODES * HEADS); // 1.6 MB
    unsigned* localx   = M + (size_t)NBLK_BIN * NBUCK;                 // 1.6 MB
    unsigned* partials = localx + T_FLAT;                              // 6 KB
    unsigned* pscan    = partials + SCANA_BLOCKS;                      // 6 KB
    unsigned* S        = pscan + SCANA_BLOCKS;                         // 1.6 MB (T_FLAT+1)
    unsigned* offs     = S + (T_FLAT + 1);                             // N+1 u32

    wcvt_kernel<<<(IN_CH * HC + 255) / 256, 256, 0, stream>>>(weight, wT);
    gemm_h_kernel<<<(N_NODES + 63) / 64, 256, 0, stream>>>(x, wT, att, h16, s_src, s_dst);
    histM_kernel<<<NBLK_BIN, 256, 0, stream>>>(ei, M);
    scanA_kernel<<<SCANA_BLOCKS, 256, 0, stream>>>(M, localx, partials);
    scanB_kernel<<<1, 256, 0, stream>>>(partials, pscan);
    scanC_kernel<<<SCANA_BLOCKS, 256, 0, stream>>>(localx, pscan, S);
    bin_kernel<<<NBLK_BIN, 256, 0, stream>>>(ei, ea, s_src, s_dst, S, slots, alpha, eif);
    sort_kernel<<<NBUCK, 256, 0, stream>>>(S, slots, slots2, offs);
    gather_kernel<<<(N_NODES + 3) / 4, 256, 0, stream>>>(
        h16, s_src, s_dst, bias, offs, slots2, alpha, out, eif);
}

// Round 16
// 161.562 us; speedup vs baseline: 1.1491x; 1.0559x over previous
//
#include <hip/hip_runtime.h>

#define N_NODES 50000
#define N_EDGES 1600000
#define IN_CH 128
#define HEADS 4
#define HC 64                      // HEADS*OUT_CH
#define E_FULL (N_EDGES + N_NODES)
#define NEG_SLOPE 0.2f

#define BUCKET_NODES 98
#define NBUCK 512                  // 512*98 = 50176 >= 50000
#define BIN_TILE 2048              // edges per bin block (256 thr x 8)
#define NBLK_BIN ((N_EDGES + BIN_TILE - 1) / BIN_TILE)   // 782
#define NBLK_GEMM ((N_NODES + 63) / 64)                  // 782
#define T_FLAT (NBUCK * NBLK_BIN)                        // 400384
#define SCANA_BLOCKS (T_FLAT / 256)                      // 1564 (exact)

typedef __attribute__((ext_vector_type(8))) short short8v;
typedef __attribute__((ext_vector_type(4))) float float4v;

__device__ __forceinline__ float leaky(float s) { return s >= 0.f ? s : NEG_SLOPE * s; }

__device__ __forceinline__ unsigned f2bf(float f) {  // round-to-nearest-even
    unsigned u = __float_as_uint(f);
    return (u + 0x7fffu + ((u >> 16) & 1u)) >> 16;
}
__device__ __forceinline__ float bf2f(unsigned v) {
    return __uint_as_float(v << 16);
}

// ---------------- Kernel W: weight f32[128][64] -> bf16 wT[64][128] -------
__global__ __launch_bounds__(256) void wcvt_kernel(
    const float* __restrict__ w, unsigned short* __restrict__ wT)
{
    int i = blockIdx.x * 256 + threadIdx.x;
    if (i < IN_CH * HC) {
        int k = i >> 6, c = i & 63;
        wT[c * IN_CH + k] = (unsigned short)f2bf(w[i]);
    }
}

// ------- Fused kernel: blocks [0,782) = MFMA GEMM; [782,1564) = histM -----
// The two halves are independent; one launch lets them overlap on the CUs.
__global__ __launch_bounds__(256) void gemm_hist_kernel(
    const float* __restrict__ x, const unsigned short* __restrict__ wT,
    const float* __restrict__ att, const int* __restrict__ ei,
    unsigned short* __restrict__ h16,
    float* __restrict__ s_src, float* __restrict__ s_dst,
    unsigned* __restrict__ M)
{
    __shared__ __align__(16) unsigned char smem[64 * 128 * 2];   // 16 KB
    const int tid = threadIdx.x;

    if (blockIdx.x < NBLK_GEMM) {
        // ================= GEMM half =================
        unsigned short* x_lds = (unsigned short*)smem;
        const int nbase = blockIdx.x * 64;

        #pragma unroll
        for (int s = 0; s < 8; ++s) {
            int i = s * 256 + tid;            // float4 unit 0..2047
            int node = i >> 5;                // 0..63
            int q = i & 31;                   // float4 within row
            float4 v = make_float4(0.f, 0.f, 0.f, 0.f);
            int gn = nbase + node;
            if (gn < N_NODES) v = ((const float4*)x)[(size_t)gn * 32 + q];
            ushort4 b;
            b.x = (unsigned short)f2bf(v.x);
            b.y = (unsigned short)f2bf(v.y);
            b.z = (unsigned short)f2bf(v.z);
            b.w = (unsigned short)f2bf(v.w);
            int chunk = q >> 1, half = q & 1;
            int sw = chunk ^ (node & 7);
            *(ushort4*)&x_lds[node * 128 + sw * 8 + half * 4] = b;
        }
        __syncthreads();

        const int wid = tid >> 6, lane = tid & 63;
        const int g = lane >> 4, m = lane & 15;
        const int rt = wid;

        float4v acc[4] = {{0.f,0.f,0.f,0.f},{0.f,0.f,0.f,0.f},
                          {0.f,0.f,0.f,0.f},{0.f,0.f,0.f,0.f}};
        #pragma unroll
        for (int kk = 0; kk < 4; ++kk) {
            int chunk = (kk * 4 + g) ^ (m & 7);
            short8v a = *(const short8v*)&x_lds[(rt * 16 + m) * 128 + chunk * 8];
            #pragma unroll
            for (int ct = 0; ct < 4; ++ct) {
                short8v bfr = *(const short8v*)&wT[(ct * 16 + m) * IN_CH + kk * 32 + g * 8];
                acc[ct] = __builtin_amdgcn_mfma_f32_16x16x32_bf16(a, bfr, acc[ct], 0, 0, 0);
            }
        }

        #pragma unroll
        for (int ct = 0; ct < 4; ++ct) {
            float as = att[ct * 32 + m];
            float ad = att[ct * 32 + 16 + m];
            float ts[4], td[4];
            #pragma unroll
            for (int r = 0; r < 4; ++r) {
                int node = nbase + rt * 16 + g * 4 + r;
                float v = acc[ct][r];
                if (node < N_NODES)
                    h16[(size_t)node * HC + ct * 16 + m] = (unsigned short)f2bf(v);
                ts[r] = v * as;
                td[r] = v * ad;
            }
            #pragma unroll
            for (int msk = 1; msk <= 8; msk <<= 1) {
                #pragma unroll
                for (int r = 0; r < 4; ++r) {
                    ts[r] += __shfl_xor(ts[r], msk, 64);
                    td[r] += __shfl_xor(td[r], msk, 64);
                }
            }
            if (m == 0) {
                #pragma unroll
                for (int r = 0; r < 4; ++r) {
                    int node = nbase + rt * 16 + g * 4 + r;
                    if (node < N_NODES) {
                        s_src[node * HEADS + ct] = ts[r];
                        s_dst[node * HEADS + ct] = td[r];
                    }
                }
            }
        }
    } else {
        // ================= hist half =================
        unsigned* lh = (unsigned*)smem;
        const int bid = blockIdx.x - NBLK_GEMM;
        for (int j = tid; j < NBUCK; j += 256) lh[j] = 0;
        __syncthreads();
        const int base = bid * BIN_TILE;
        #pragma unroll
        for (int k = 0; k < 8; ++k) {
            int e = base + k * 256 + tid;
            if (e < N_EDGES)
                atomicAdd(&lh[(unsigned)ei[e] / BUCKET_NODES], 1u);
        }
        __syncthreads();
        unsigned* Mb = M + (size_t)bid * NBUCK;
        for (int j = tid; j < NBUCK; j += 256) Mb[j] = lh[j];
    }
}

// ---------------- Scan over flattened [bucket][block] counts ---------------
__device__ __forceinline__ unsigned block_excl_scan(unsigned v, unsigned* total,
                                                    int tid) {
    const int lane = tid & 63, wid = tid >> 6;
    unsigned x = v;
    #pragma unroll
    for (int d = 1; d < 64; d <<= 1) {
        unsigned t = __shfl_up(x, d, 64);
        if (lane >= d) x += t;
    }
    __shared__ unsigned wsum[4];
    if (lane == 63) wsum[wid] = x;
    __syncthreads();
    unsigned woff = 0;
    for (int i = 0; i < wid; ++i) woff += wsum[i];
    unsigned incl = x + woff;
    if (tid == 255) *total = incl;
    return incl - v;
}

__global__ __launch_bounds__(256) void scanA_kernel(
    const unsigned* __restrict__ M, unsigned* __restrict__ localx,
    unsigned* __restrict__ partials)
{
    const int tid = threadIdx.x;
    const int f = blockIdx.x * 256 + tid;   // flat = bucket*NBLK_BIN + block
    unsigned v = 0;
    if (f < T_FLAT) {
        int bucket = f / NBLK_BIN;
        int blk = f - bucket * NBLK_BIN;
        v = M[(size_t)blk * NBUCK + bucket];
    }
    __shared__ unsigned tot;
    unsigned excl = block_excl_scan(v, &tot, tid);
    if (f < T_FLAT) localx[f] = excl;
    __syncthreads();
    if (tid == 0) partials[blockIdx.x] = tot;
}

__global__ __launch_bounds__(256) void scanB_kernel(
    const unsigned* __restrict__ partials, unsigned* __restrict__ pscan)
{
    __shared__ unsigned tot_sh;
    __shared__ unsigned carry_sh;
    const int tid = threadIdx.x;
    if (tid == 0) carry_sh = 0;
    __syncthreads();
    const int nchunk = (SCANA_BLOCKS + 255) / 256;
    for (int ch = 0; ch < nchunk; ++ch) {
        int i = ch * 256 + tid;
        unsigned v = (i < SCANA_BLOCKS) ? partials[i] : 0u;
        unsigned excl = block_excl_scan(v, &tot_sh, tid);
        unsigned carry = carry_sh;
        if (i < SCANA_BLOCKS) pscan[i] = excl + carry;
        __syncthreads();
        if (tid == 0) carry_sh += tot_sh;
        __syncthreads();
    }
}

// S[f] (old scanC output) is now computed inline: localx[f] + pscan[f>>8]
__device__ __forceinline__ unsigned S_at(const unsigned* __restrict__ localx,
                                         const unsigned* __restrict__ pscan,
                                         unsigned f) {
    return (f >= (unsigned)T_FLAT) ? (unsigned)N_EDGES
                                   : localx[f] + pscan[f >> 8];
}

// ---------------- Kernel D: bin pass — alpha + eif + grouped slot writes --
__global__ __launch_bounds__(256) void bin_kernel(
    const int* __restrict__ ei, const float* __restrict__ ea,
    const float* __restrict__ s_src, const float* __restrict__ s_dst,
    const unsigned* __restrict__ localx, const unsigned* __restrict__ pscan,
    uint4* __restrict__ slots, float* __restrict__ alpha,
    float* __restrict__ eif)
{
    __shared__ unsigned lh[NBUCK];
    __shared__ unsigned lbase[NBUCK];
    const int tid = threadIdx.x;
    for (int j = tid; j < NBUCK; j += 256) lh[j] = 0;
    __syncthreads();

    const int base = blockIdx.x * BIN_TILE;
    unsigned b8[8], idx8[8], p0[8], p1[8], p2[8];
    #pragma unroll
    for (int k = 0; k < 8; ++k) {
        int e = base + k * 256 + tid;
        b8[k] = 0xffffffffu;
        if (e < N_EDGES) {
            unsigned r = (unsigned)ei[e];
            unsigned c = (unsigned)ei[N_EDGES + e];
            float4 ss = ((const float4*)s_src)[r];
            float4 sd = ((const float4*)s_dst)[c];
            float4 eav = ((const float4*)ea)[e];
            float4 a;
            a.x = leaky(ss.x + sd.x) * eav.x;
            a.y = leaky(ss.y + sd.y) * eav.y;
            a.z = leaky(ss.z + sd.z) * eav.z;
            a.w = leaky(ss.w + sd.w) * eav.w;
            ((float4*)alpha)[e] = a;
            eif[e] = (float)r;
            eif[(size_t)E_FULL + e] = (float)c;

            unsigned bk = r / BUCKET_NODES;
            unsigned rl = r - bk * BUCKET_NODES;
            b8[k] = bk;
            p0[k] = c | (rl << 16);
            p1[k] = f2bf(a.x) | (f2bf(a.y) << 16);
            p2[k] = f2bf(a.z) | (f2bf(a.w) << 16);
            idx8[k] = atomicAdd(&lh[bk], 1u);
        }
    }
    __syncthreads();
    for (int j = tid; j < NBUCK; j += 256) {
        unsigned f = (unsigned)j * NBLK_BIN + blockIdx.x;
        lbase[j] = localx[f] + pscan[f >> 8];
    }
    __syncthreads();
    #pragma unroll
    for (int k = 0; k < 8; ++k) {
        if (b8[k] != 0xffffffffu)
            slots[lbase[b8[k]] + idx8[k]] = make_uint4(p0[k], p1[k], p2[k], 0u);
    }
}

// ---------------- Kernel S: per-bucket counting sort -> node-sorted slots --
__global__ __launch_bounds__(256) void sort_kernel(
    const unsigned* __restrict__ localx, const unsigned* __restrict__ pscan,
    const uint4* __restrict__ slots, uint4* __restrict__ slots2,
    unsigned* __restrict__ offs)
{
    __shared__ unsigned cnt[BUCKET_NODES];
    __shared__ unsigned cur[BUCKET_NODES];
    const int b = blockIdx.x;
    const int tid = threadIdx.x;
    const unsigned start = S_at(localx, pscan, (unsigned)b * NBLK_BIN);
    const unsigned end   = S_at(localx, pscan, (unsigned)(b + 1) * NBLK_BIN);

    for (int j = tid; j < BUCKET_NODES; j += 256) cnt[j] = 0;
    __syncthreads();
    for (unsigned i = start + tid; i < end; i += 256)
        atomicAdd(&cnt[slots[i].x >> 16], 1u);
    __syncthreads();
    if (tid == 0) {
        unsigned run = 0;
        for (int j = 0; j < BUCKET_NODES; ++j) {
            unsigned c = cnt[j];
            cur[j] = run;
            run += c;
        }
    }
    __syncthreads();
    const int nstart = b * BUCKET_NODES;
    for (int j = tid; j < BUCKET_NODES; j += 256) {
        int n = nstart + j;
        if (n <= N_NODES) offs[n] = start + cur[j];
    }
    __syncthreads();
    for (unsigned i = start + tid; i < end; i += 256) {
        uint4 s = slots[i];
        unsigned rl = s.x >> 16;
        unsigned pos = start + atomicAdd(&cur[rl], 1u);
        slots2[pos] = s;
    }
}

// ---------------- Kernel E: per-node register gather (8-deep MLP) ---------
__device__ __forceinline__ float slot_alpha(uint4 s, int hd) {
    unsigned w = (hd & 2) ? s.z : s.y;
    return bf2f((hd & 1) ? (w >> 16) : (w & 0xffffu));
}

__global__ __launch_bounds__(256) void gather_kernel(
    const unsigned short* __restrict__ h16, const float* __restrict__ s_src,
    const float* __restrict__ s_dst, const float* __restrict__ bias,
    const unsigned* __restrict__ offs, const uint4* __restrict__ slots2,
    float* __restrict__ alpha, float* __restrict__ out, float* __restrict__ eif)
{
    const int tid = threadIdx.x;
    const int n = blockIdx.x * 4 + (tid >> 6);
    if (n >= N_NODES) return;
    const int lane = tid & 63, hd = lane >> 4;

    float s_self = s_src[n * HEADS + hd] + s_dst[n * HEADS + hd];
    float acc = bias[lane] + leaky(s_self) * bf2f(h16[(size_t)n * HC + lane]);

    const unsigned start = offs[n];
    const int cnt = (int)(offs[n + 1] - start);

    int i = 0;
    for (; i + 7 < cnt; i += 8) {
        uint4 sl[8];
        float hv[8];
        #pragma unroll
        for (int u = 0; u < 8; ++u) sl[u] = slots2[start + i + u];
        #pragma unroll
        for (int u = 0; u < 8; ++u)
            hv[u] = bf2f(h16[(size_t)(sl[u].x & 0xffffu) * HC + lane]);
        #pragma unroll
        for (int u = 0; u < 8; ++u)
            acc = fmaf(slot_alpha(sl[u], hd), hv[u], acc);
    }
    for (; i < cnt; ++i) {
        uint4 s0 = slots2[start + i];
        float h0 = bf2f(h16[(size_t)(s0.x & 0xffffu) * HC + lane]);
        acc = fmaf(slot_alpha(s0, hd), h0, acc);
    }
    out[(size_t)n * HC + lane] = acc;

    if (lane < HEADS) {
        float s2 = s_src[n * HEADS + lane] + s_dst[n * HEADS + lane];
        alpha[(size_t)(N_EDGES + n) * HEADS + lane] = leaky(s2);
    }
    if (lane == 4) eif[N_EDGES + n] = (float)n;
    if (lane == 5) eif[(size_t)E_FULL + N_EDGES + n] = (float)n;
}

extern "C" void kernel_launch(void* const* d_in, const int* in_sizes, int n_in,
                              void* d_out, int out_size, void* d_ws, size_t ws_size,
                              hipStream_t stream) {
    const float* x      = (const float*)d_in[0];
    const int*   ei     = (const int*)  d_in[1];
    const float* ea     = (const float*)d_in[2];
    const float* weight = (const float*)d_in[3];
    const float* att    = (const float*)d_in[4];
    const float* bias   = (const float*)d_in[5];

    float* out   = (float*)d_out;                    // N_NODES*HC
    float* eif   = out + (size_t)N_NODES * HC;       // 2*E_FULL (as float)
    float* alpha = eif + (size_t)2 * E_FULL;         // E_FULL*HEADS

    // workspace layout (uint4 arrays first for 16B alignment); ~63 MB total
    uint4* slots  = (uint4*)d_ws;                                      // 25.6 MB
    uint4* slots2 = slots + (size_t)N_EDGES;                           // 25.6 MB
    unsigned short* wT = (unsigned short*)(slots2 + (size_t)N_EDGES);  // 16 KB
    unsigned short* h16 = wT + (size_t)IN_CH * HC;                     // 6.4 MB
    float* s_src = (float*)(h16 + (size_t)N_NODES * HC);               // 0.8 MB
    float* s_dst = s_src + (size_t)N_NODES * HEADS;                    // 0.8 MB
    unsigned* M        = (unsigned*)(s_dst + (size_t)N_NODES * HEADS); // 1.6 MB
    unsigned* localx   = M + (size_t)NBLK_BIN * NBUCK;                 // 1.6 MB
    unsigned* partials = localx + T_FLAT;                              // 6 KB
    unsigned* pscan    = partials + SCANA_BLOCKS;                      // 6 KB
    unsigned* offs     = pscan + SCANA_BLOCKS;                         // N+1 u32

    wcvt_kernel<<<(IN_CH * HC + 255) / 256, 256, 0, stream>>>(weight, wT);
    gemm_hist_kernel<<<NBLK_GEMM + NBLK_BIN, 256, 0, stream>>>(
        x, wT, att, ei, h16, s_src, s_dst, M);
    scanA_kernel<<<SCANA_BLOCKS, 256, 0, stream>>>(M, localx, partials);
    scanB_kernel<<<1, 256, 0, stream>>>(partials, pscan);
    bin_kernel<<<NBLK_BIN, 256, 0, stream>>>(
        ei, ea, s_src, s_dst, localx, pscan, slots, alpha, eif);
    sort_kernel<<<NBUCK, 256, 0, stream>>>(localx, pscan, slots, slots2, offs);
    gather_kernel<<<(N_NODES + 3) / 4, 256, 0, stream>>>(
        h16, s_src, s_dst, bias, offs, slots2, alpha, out, eif);
}